// Round 6
// baseline (187.234 us; speedup 1.0000x reference)
//
#include <hip/hip_runtime.h>

// =============================================================================
// MEASUREMENT ROUND: identical to round-4 pipeline, but k_region is launched
// TWICE (idempotent: reads only ws, fully overwrites out with same values).
//   region_time = dur_this_round - 113.3us ;  place_time = 113.3 - region - 2
// =============================================================================

#define BOX   256
#define NCLS  2
#define BATCH 2
#define NPTS  262144                      // 2^18
#define VOL   (BOX * BOX * BOX)
#define NBINS (BATCH * BOX * BOX)         // (b, base_z, base_y) row-bins = 131072
#define CAP   32                          // records per bin (Poisson mean 4)
#define CAPSH 5
#define RY    16                          // rows per region tile
#define NT    (BOX / RY)                  // 16 y-tiles per plane
#define NREG  (BATCH * BOX * NT)          // 8192 region blocks
#define NBMETA 34                         // 2 planes x 17 rows per region

__global__ __launch_bounds__(256) void k_zero(float4* __restrict__ p, int n4)
{
    const int stride = gridDim.x * 256;
    for (int i = blockIdx.x * 256 + threadIdx.x; i < n4; i += stride)
        p[i] = make_float4(0.f, 0.f, 0.f, 0.f);
}

// ---------------------------------------------------------------------------
// Pass 1: one atomic per point -> slot in capacity-binned record array.
// Record = {px, pack16(ry,rz), v0, v1} (16 B).
// ---------------------------------------------------------------------------
__global__ __launch_bounds__(256) void k_place(const float* __restrict__ pts,
                                               const float* __restrict__ vals,
                                               unsigned* __restrict__ cursor,
                                               float4* __restrict__ rec,
                                               float4* __restrict__ ovf4,
                                               unsigned* __restrict__ ovfbin,
                                               unsigned* __restrict__ ovfcnt)
{
    const int tid = blockIdx.x * 256 + threadIdx.x;   // exactly BATCH*NPTS threads
    const int b = tid >> 18;
    const int n = tid & (NPTS - 1);

    const float* pp = pts + ((size_t)b * NPTS + n) * 3;
    const float px = (pp[0] + 0.5f) * (float)BOX;
    const float py = (pp[1] + 0.5f) * (float)BOX;
    const float pz = (pp[2] + 0.5f) * (float)BOX;

    const float fy = floorf(py), fz = floorf(pz);
    const int by = (int)fy, bz = (int)fz;
    const float ry = py - fy, rz = pz - fz;

    const unsigned qy = (unsigned)(ry * 65536.0f);
    const unsigned qz = (unsigned)(rz * 65536.0f);
    const unsigned packed = (qz << 16) | (qy & 0xffffu);

    const float v0 = vals[((size_t)b * NCLS + 0) * NPTS + n];
    const float v1 = vals[((size_t)b * NCLS + 1) * NPTS + n];
    const float4 r = make_float4(px, __uint_as_float(packed), v0, v1);

    const unsigned bin = ((unsigned)b << 16) | ((unsigned)bz << 8) | (unsigned)by;
    const unsigned slot = atomicAdd(&cursor[bin], 1u);
    if (slot < CAP) {
        rec[((size_t)bin << CAPSH) + slot] = r;
    } else {
        const unsigned o = atomicAdd(ovfcnt, 1u);
        ovf4[o] = r;
        ovfbin[o] = bin;
    }
}

// ---------------------------------------------------------------------------
// Pass 2: one block per (b, z-plane P, y-tile T).
// ---------------------------------------------------------------------------
__global__ __launch_bounds__(512) void k_region(const float4* __restrict__ rec,
                                                const unsigned* __restrict__ cursor,
                                                const float4* __restrict__ ovf4,
                                                const unsigned* __restrict__ ovfbin,
                                                const unsigned* __restrict__ ovfcnt,
                                                float* __restrict__ out)
{
    __shared__ float acc[NCLS * RY * BOX];      // 32 KB
    __shared__ unsigned s_bin[NBMETA];
    __shared__ unsigned s_len[NBMETA];
    __shared__ unsigned s_pfx[NBMETA + 1];

    const int tid = threadIdx.x;
    const int bid = blockIdx.x;
    const int b = bid >> 12;
    const int P = (bid >> 4) & 255;             // owned z-plane
    const int T = bid & 15;                     // owned y-tile (rows RY*T..RY*T+15)

    {
        float4* a4 = (float4*)acc;
        #pragma unroll
        for (int i = 0; i < 4; ++i)
            a4[i * 512 + tid] = make_float4(0.f, 0.f, 0.f, 0.f);
    }

    if (tid < NBMETA) {
        const int j = tid;
        const int zsrc = P - 1 + (j >= 17 ? 1 : 0);
        const int y0 = RY * T - 1 + (j >= 17 ? j - 17 : j);
        unsigned bin = 0, len = 0;
        if (zsrc >= 0 && y0 >= 0 && y0 < BOX) {
            bin = ((unsigned)b << 16) | ((unsigned)zsrc << 8) | (unsigned)y0;
            len = cursor[bin];
            if (len > CAP) len = CAP;
        }
        s_bin[j] = bin;
        s_len[j] = len;
    }
    __syncthreads();

    if (tid < 64) {
        const unsigned own = (tid < NBMETA) ? s_len[tid] : 0u;
        unsigned v = own;
        #pragma unroll
        for (int off = 1; off < 64; off <<= 1) {
            const unsigned t = __shfl_up(v, off, 64);
            if (tid >= off) v += t;
        }
        if (tid < NBMETA) s_pfx[tid] = v - own;
        if (tid == NBMETA - 1) s_pfx[NBMETA] = v;
    }
    __syncthreads();

    const int R = (int)s_pfx[NBMETA];
    for (int r = tid; r < R; r += 512) {
        int lo = 0, hi = NBMETA - 1;
        while (lo < hi) {
            const int mid = (lo + hi + 1) >> 1;
            if ((int)s_pfx[mid] <= r) lo = mid; else hi = mid - 1;
        }
        const size_t idx = ((size_t)s_bin[lo] << CAPSH) + (unsigned)(r - (int)s_pfx[lo]);
        const float4 q = rec[idx];

        const unsigned pk = __float_as_uint(q.y);
        const float ry = (float)(pk & 0xffffu) * (1.0f / 65536.0f);
        const float rz = (float)(pk >> 16) * (1.0f / 65536.0f);
        const float fx = floorf(q.x);
        const float rx = q.x - fx;
        const int ix = (int)fx;

        const float wz = (lo >= 17) ? (1.0f - rz) : rz;
        const int yy0 = (lo >= 17 ? lo - 17 : lo) - 1;

        #pragma unroll
        for (int dy = 0; dy < 2; ++dy) {
            const int yy = yy0 + dy;
            if ((unsigned)yy < RY) {
                const float wzy = wz * (dy ? ry : 1.0f - ry);
                #pragma unroll
                for (int dx = 0; dx < 2; ++dx) {
                    const int x = ix + dx;
                    if (x < BOX) {
                        const float w = wzy * (dx ? rx : 1.0f - rx);
                        const int li = yy * BOX + x;
                        atomicAdd(&acc[li], w * q.z);
                        atomicAdd(&acc[RY * BOX + li], w * q.w);
                    }
                }
            }
        }
    }

    const int oc = (int)*ovfcnt;
    for (int r = tid; r < oc; r += 512) {
        const unsigned bin = ovfbin[r];
        if ((int)(bin >> 16) != b) continue;
        const int bz = (int)((bin >> 8) & 255u);
        if (bz != P && bz != P - 1) continue;
        const int by = (int)(bin & 255u);
        const int yy0 = by - RY * T;
        if (yy0 < -1 || yy0 > RY - 1) continue;

        const float4 q = ovf4[r];
        const unsigned pk = __float_as_uint(q.y);
        const float ry = (float)(pk & 0xffffu) * (1.0f / 65536.0f);
        const float rz = (float)(pk >> 16) * (1.0f / 65536.0f);
        const float fx = floorf(q.x);
        const float rx = q.x - fx;
        const int ix = (int)fx;
        const float wz = (bz == P) ? (1.0f - rz) : rz;

        for (int dy = 0; dy < 2; ++dy) {
            const int yy = yy0 + dy;
            if ((unsigned)yy < RY) {
                const float wzy = wz * (dy ? ry : 1.0f - ry);
                for (int dx = 0; dx < 2; ++dx) {
                    const int x = ix + dx;
                    if (x < BOX) {
                        const float w = wzy * (dx ? rx : 1.0f - rx);
                        const int li = yy * BOX + x;
                        atomicAdd(&acc[li], w * q.z);
                        atomicAdd(&acc[RY * BOX + li], w * q.w);
                    }
                }
            }
        }
    }
    __syncthreads();

    #pragma unroll
    for (int c = 0; c < NCLS; ++c) {
        const size_t o4base = (size_t)((b * NCLS + c) * BOX + P) * (BOX * BOX / 4)
                              + (size_t)T * (RY * BOX / 4);
        float4* o4 = (float4*)out;
        const float4* a4 = (const float4*)(acc + c * RY * BOX);
        #pragma unroll
        for (int i = 0; i < 2; ++i)
            o4[o4base + i * 512 + tid] = a4[i * 512 + tid];
    }
}

__global__ __launch_bounds__(256) void cic_scatter_kernel(
    const float* __restrict__ points, const float* __restrict__ values,
    float* __restrict__ out)
{
    const int tid = blockIdx.x * blockDim.x + threadIdx.x;
    if (tid >= BATCH * NPTS) return;
    const int b = tid >> 18, n = tid & (NPTS - 1);
    const float* pp = points + (size_t)tid * 3;
    const float px = (pp[0] + 0.5f) * BOX, py = (pp[1] + 0.5f) * BOX, pz = (pp[2] + 0.5f) * BOX;
    const float fx = floorf(px), fy = floorf(py), fz = floorf(pz);
    const float rx = px - fx, ry = py - fy, rz = pz - fz;
    const int ix = (int)fx, iy = (int)fy, iz = (int)fz;
    const float v0 = values[(size_t)(b * 2) * NPTS + n];
    const float v1 = values[(size_t)(b * 2 + 1) * NPTS + n];
    const float wx[2] = {1.f - rx, rx}, wy[2] = {1.f - ry, ry}, wz[2] = {1.f - rz, rz};
    float* out0 = out + (size_t)(b * 2) * VOL;
    float* out1 = out + (size_t)(b * 2 + 1) * VOL;
    for (int dz = 0; dz < 2; ++dz) {
        const int z = iz + dz; if (z >= BOX) continue;
        for (int dy = 0; dy < 2; ++dy) {
            const int y = iy + dy; if (y >= BOX) continue;
            const float wzy = wz[dz] * wy[dy];
            const int rowbase = (z * BOX + y) * BOX;
            for (int dx = 0; dx < 2; ++dx) {
                const int x = ix + dx; if (x >= BOX) continue;
                atomicAdd(out0 + rowbase + x, wzy * wx[dx] * v0);
                atomicAdd(out1 + rowbase + x, wzy * wx[dx] * v1);
            }
        }
    }
}

extern "C" void kernel_launch(void* const* d_in, const int* in_sizes, int n_in,
                              void* d_out, int out_size, void* d_ws, size_t ws_size,
                              hipStream_t stream) {
    const float* points = (const float*)d_in[0];   // [B, N, 3]
    const float* values = (const float*)d_in[1];   // [B, C, N]
    float* out = (float*)d_out;                    // [B, C, 256,256,256]

    const size_t CUR_OFF  = 0;                                   // NBINS u32
    const size_t OVFC_OFF = (size_t)NBINS * 4;                   // 1 u32 (+pad)
    const size_t REC_OFF  = OVFC_OFF + 256;                      // NBINS*CAP float4
    const size_t OVF4_OFF = REC_OFF + (size_t)NBINS * CAP * 16;
    const size_t OVFB_OFF = OVF4_OFF + (size_t)BATCH * NPTS * 16;
    const size_t WS_NEED  = OVFB_OFF + (size_t)BATCH * NPTS * 4;

    if (ws_size < WS_NEED) {
        hipMemsetAsync(out, 0, (size_t)out_size * sizeof(float), stream);
        cic_scatter_kernel<<<(BATCH * NPTS) / 256, 256, 0, stream>>>(points, values, out);
        return;
    }

    char* ws = (char*)d_ws;
    unsigned* cursor = (unsigned*)(ws + CUR_OFF);
    unsigned* ovfcnt = (unsigned*)(ws + OVFC_OFF);
    float4*   rec    = (float4*)(ws + REC_OFF);
    float4*   ovf4   = (float4*)(ws + OVF4_OFF);
    unsigned* ovfbin = (unsigned*)(ws + OVFB_OFF);

    const int n4 = (int)((OVFC_OFF + 256) / 16);
    k_zero<<<256, 256, 0, stream>>>((float4*)ws, n4);

    k_place<<<(BATCH * NPTS) / 256, 256, 0, stream>>>(points, values, cursor,
                                                      rec, ovf4, ovfbin, ovfcnt);
    k_region<<<NREG, 512, 0, stream>>>(rec, cursor, ovf4, ovfbin, ovfcnt, out);
    // MEASUREMENT: second identical launch (idempotent full overwrite of out).
    // region_time = dur_this_round - 113.3us (round-4 baseline).
    k_region<<<NREG, 512, 0, stream>>>(rec, cursor, ovf4, ovfbin, ovfcnt, out);
}

// Round 8
// 101.679 us; speedup vs baseline: 1.8414x; 1.8414x over previous
//
#include <hip/hip_runtime.h>

#define BOX   256
#define NCLS  2
#define BATCH 2
#define NPTS  262144                      // 2^18
#define VOL   (BOX * BOX * BOX)
#define NPTOT (BATCH * NPTS)
#define NBINS (BATCH * BOX * BOX)         // (b, base_z, base_y) row-bins = 131072
#define CAP   16                          // records per bin (Poisson mean 4)
#define CAPSH 4
#define RY    16                          // rows per region tile
#define NT    (BOX / RY)                  // 16 y-tiles per plane
#define NREG  (BATCH * BOX * NT)          // 8192 region blocks
#define NBMETA 34                         // 2 planes x 17 rows per region

typedef float vfloat4 __attribute__((ext_vector_type(4)));   // clang-native for NT stores

__global__ __launch_bounds__(256) void k_zero(float4* __restrict__ p, int n4)
{
    const int i = blockIdx.x * 256 + threadIdx.x;
    if (i < n4) p[i] = make_float4(0.f, 0.f, 0.f, 0.f);
}

// ---------------------------------------------------------------------------
// Pass 1: one atomic per point -> slot in capacity-binned record array.
// Record = {px, pack16(ry,rz), v0, v1} (16 B). Overflow (~1e-6/bin) -> list.
// ---------------------------------------------------------------------------
__global__ __launch_bounds__(256) void k_place(const float* __restrict__ pts,
                                               const float* __restrict__ vals,
                                               unsigned* __restrict__ cursor,
                                               float4* __restrict__ rec,
                                               float4* __restrict__ ovf4,
                                               unsigned* __restrict__ ovfbin,
                                               unsigned* __restrict__ ovfcnt)
{
    const int tid = blockIdx.x * 256 + threadIdx.x;   // exactly NPTOT threads
    const int b = tid >> 18;
    const int n = tid & (NPTS - 1);

    const float* pp = pts + (size_t)tid * 3;
    const float px = (pp[0] + 0.5f) * (float)BOX;
    const float py = (pp[1] + 0.5f) * (float)BOX;
    const float pz = (pp[2] + 0.5f) * (float)BOX;

    const float fy = floorf(py), fz = floorf(pz);
    const int by = (int)fy, bz = (int)fz;
    const float ry = py - fy, rz = pz - fz;

    const unsigned qy = (unsigned)(ry * 65536.0f);
    const unsigned qz = (unsigned)(rz * 65536.0f);
    const unsigned packed = (qz << 16) | (qy & 0xffffu);

    const float v0 = vals[(size_t)(b * 2) * NPTS + n];
    const float v1 = vals[(size_t)(b * 2 + 1) * NPTS + n];
    const float4 r = make_float4(px, __uint_as_float(packed), v0, v1);

    const unsigned bin = ((unsigned)b << 16) | ((unsigned)bz << 8) | (unsigned)by;
    const unsigned slot = atomicAdd(&cursor[bin], 1u);
    if (slot < CAP) {
        rec[((size_t)bin << CAPSH) + slot] = r;
    } else {
        const unsigned o = atomicAdd(ovfcnt, 1u);
        ovf4[o] = r;
        ovfbin[o] = bin;
    }
}

// ---------------------------------------------------------------------------
// Pass 2: one block per (b, z-plane P, y-tile T). ONE-SHOT gather:
// thread (j = tid>>4, k = tid&15) handles record k of source-bin j.
// 32 bins covered directly; bins 32,33 by wave 0's lanes. No scan, no
// binary search, 2 barriers total. Non-temporal coalesced output stores.
// ---------------------------------------------------------------------------
__global__ __launch_bounds__(512) void k_region(const float4* __restrict__ rec,
                                                const unsigned* __restrict__ cursor,
                                                const float4* __restrict__ ovf4,
                                                const unsigned* __restrict__ ovfbin,
                                                const unsigned* __restrict__ ovfcnt,
                                                float* __restrict__ out)
{
    __shared__ float acc[NCLS * RY * BOX];      // 32 KB
    __shared__ unsigned s_base[NBMETA];         // bin*CAP (record base index)
    __shared__ unsigned s_len[NBMETA];

    const int t = threadIdx.x;
    const int bid = blockIdx.x;
    const int b = bid >> 12;
    const int P = (bid >> 4) & 255;             // owned z-plane
    const int T = bid & 15;                     // owned y-tile

    {
        float4* a4 = (float4*)acc;
        #pragma unroll
        for (int i = 0; i < 4; ++i)
            a4[i * 512 + t] = make_float4(0.f, 0.f, 0.f, 0.f);
    }

    // meta: j in [0,34): plane = P-1 + (j>=17), row y0 = 16T-1 + (j%17).
    // cursor addresses for consecutive y are contiguous -> few transactions.
    if (t < NBMETA) {
        const int ps = (t >= 17);
        const int zsrc = P - 1 + ps;
        const int y0 = RY * T - 1 + (t - 17 * ps);
        unsigned base = 0, len = 0;
        if (zsrc >= 0 && y0 >= 0) {             // y0 <= 16*15+15 = 255 always
            const unsigned bin = ((unsigned)b << 16) | ((unsigned)zsrc << 8) | (unsigned)y0;
            len = cursor[bin];
            if (len > CAP) len = CAP;
            base = bin << CAPSH;
        }
        s_base[t] = base;
        s_len[t] = len;
    }
    __syncthreads();

    // one-shot record processing
    {
        auto process = [&](int j, int k) {
            if (k < (int)s_len[j]) {
                const float4 q = rec[(size_t)s_base[j] + k];
                const unsigned pk = __float_as_uint(q.y);
                const float ry = (float)(pk & 0xffffu) * (1.0f / 65536.0f);
                const float rz = (float)(pk >> 16) * (1.0f / 65536.0f);
                const float fx = floorf(q.x);
                const float rx = q.x - fx;
                const int ix = (int)fx;
                const int ps = (j >= 17);
                const float wz = ps ? (1.0f - rz) : rz;
                const int yy0 = (j - 17 * ps) - 1;
                #pragma unroll
                for (int dy = 0; dy < 2; ++dy) {
                    const int yy = yy0 + dy;
                    if ((unsigned)yy < RY) {
                        const float wzy = wz * (dy ? ry : 1.0f - ry);
                        #pragma unroll
                        for (int dx = 0; dx < 2; ++dx) {
                            const int x = ix + dx;
                            if (x < BOX) {
                                const float w = wzy * (dx ? rx : 1.0f - rx);
                                const int li = yy * BOX + x;
                                atomicAdd(&acc[li], w * q.z);
                                atomicAdd(&acc[RY * BOX + li], w * q.w);
                            }
                        }
                    }
                }
            }
        };
        process(t >> 4, t & 15);                    // bins 0..31
        if (t < 32) process(32 + (t >> 4), t & 15); // bins 32,33 (wave 0)
    }

    // overflow records (essentially never populated; correctness path)
    const int oc = (int)*ovfcnt;
    for (int r = t; r < oc; r += 512) {
        const unsigned bin = ovfbin[r];
        if ((int)(bin >> 16) != b) continue;
        const int bz = (int)((bin >> 8) & 255u);
        if (bz != P && bz != P - 1) continue;
        const int by = (int)(bin & 255u);
        const int yy0 = by - RY * T;
        if (yy0 < -1 || yy0 > RY - 1) continue;

        const float4 q = ovf4[r];
        const unsigned pk = __float_as_uint(q.y);
        const float ry = (float)(pk & 0xffffu) * (1.0f / 65536.0f);
        const float rz = (float)(pk >> 16) * (1.0f / 65536.0f);
        const float fx = floorf(q.x);
        const float rx = q.x - fx;
        const int ix = (int)fx;
        const float wz = (bz == P) ? (1.0f - rz) : rz;

        for (int dy = 0; dy < 2; ++dy) {
            const int yy = yy0 + dy;
            if ((unsigned)yy < RY) {
                const float wzy = wz * (dy ? ry : 1.0f - ry);
                for (int dx = 0; dx < 2; ++dx) {
                    const int x = ix + dx;
                    if (x < BOX) {
                        const float w = wzy * (dx ? rx : 1.0f - rx);
                        const int li = yy * BOX + x;
                        atomicAdd(&acc[li], w * q.z);
                        atomicAdd(&acc[RY * BOX + li], w * q.w);
                    }
                }
            }
        }
    }
    __syncthreads();

    // non-temporal coalesced store: output written once, never re-read ->
    // don't thrash L2/L3 (keeps the 33 MB rec array cache-resident).
    #pragma unroll
    for (int c = 0; c < NCLS; ++c) {
        const size_t o4base = (size_t)((b * NCLS + c) * BOX + P) * (BOX * BOX / 4)
                              + (size_t)T * (RY * BOX / 4);
        vfloat4* o4 = (vfloat4*)out;
        const vfloat4* a4 = (const vfloat4*)(acc + c * RY * BOX);
        #pragma unroll
        for (int i = 0; i < 2; ++i)
            __builtin_nontemporal_store(a4[i * 512 + t], &o4[o4base + i * 512 + t]);
    }
}

// ---------------------------------------------------------------------------
// Fallback: plain global-atomic scatter (only if ws too small).
// ---------------------------------------------------------------------------
__global__ __launch_bounds__(256) void cic_scatter_kernel(
    const float* __restrict__ points, const float* __restrict__ values,
    float* __restrict__ out)
{
    const int tid = blockIdx.x * blockDim.x + threadIdx.x;
    if (tid >= NPTOT) return;
    const int b = tid >> 18, n = tid & (NPTS - 1);
    const float* pp = points + (size_t)tid * 3;
    const float px = (pp[0] + 0.5f) * BOX, py = (pp[1] + 0.5f) * BOX, pz = (pp[2] + 0.5f) * BOX;
    const float fx = floorf(px), fy = floorf(py), fz = floorf(pz);
    const float rx = px - fx, ry = py - fy, rz = pz - fz;
    const int ix = (int)fx, iy = (int)fy, iz = (int)fz;
    const float v0 = values[(size_t)(b * 2) * NPTS + n];
    const float v1 = values[(size_t)(b * 2 + 1) * NPTS + n];
    const float wx[2] = {1.f - rx, rx}, wy[2] = {1.f - ry, ry}, wz[2] = {1.f - rz, rz};
    float* out0 = out + (size_t)(b * 2) * VOL;
    float* out1 = out + (size_t)(b * 2 + 1) * VOL;
    for (int dz = 0; dz < 2; ++dz) {
        const int z = iz + dz; if (z >= BOX) continue;
        for (int dy = 0; dy < 2; ++dy) {
            const int y = iy + dy; if (y >= BOX) continue;
            const float wzy = wz[dz] * wy[dy];
            const int rowbase = (z * BOX + y) * BOX;
            for (int dx = 0; dx < 2; ++dx) {
                const int x = ix + dx; if (x >= BOX) continue;
                atomicAdd(out0 + rowbase + x, wzy * wx[dx] * v0);
                atomicAdd(out1 + rowbase + x, wzy * wx[dx] * v1);
            }
        }
    }
}

extern "C" void kernel_launch(void* const* d_in, const int* in_sizes, int n_in,
                              void* d_out, int out_size, void* d_ws, size_t ws_size,
                              hipStream_t stream) {
    const float* points = (const float*)d_in[0];   // [B, N, 3]
    const float* values = (const float*)d_in[1];   // [B, C, N]
    float* out = (float*)d_out;                    // [B, C, 256,256,256]

    const size_t CUR_OFF  = 0;                                   // NBINS u32
    const size_t OVFC_OFF = (size_t)NBINS * 4;                   // 1 u32 (+pad)
    const size_t REC_OFF  = OVFC_OFF + 256;                      // NBINS*CAP*16 B
    const size_t OVF4_OFF = REC_OFF + (size_t)NBINS * CAP * 16;
    const size_t OVFB_OFF = OVF4_OFF + (size_t)NPTOT * 16;
    const size_t WS_NEED  = OVFB_OFF + (size_t)NPTOT * 4;

    if (ws_size < WS_NEED) {
        (void)hipMemsetAsync(out, 0, (size_t)out_size * sizeof(float), stream);
        cic_scatter_kernel<<<NPTOT / 256, 256, 0, stream>>>(points, values, out);
        return;
    }

    char* ws = (char*)d_ws;
    unsigned* cursor = (unsigned*)(ws + CUR_OFF);
    unsigned* ovfcnt = (unsigned*)(ws + OVFC_OFF);
    float4*   rec    = (float4*)(ws + REC_OFF);
    float4*   ovf4   = (float4*)(ws + OVF4_OFF);
    unsigned* ovfbin = (unsigned*)(ws + OVFB_OFF);

    const int n4 = (int)((OVFC_OFF + 256) / 16);   // 32784 float4s
    k_zero<<<(n4 + 255) / 256, 256, 0, stream>>>((float4*)ws, n4);

    k_place<<<NPTOT / 256, 256, 0, stream>>>(points, values, cursor,
                                             rec, ovf4, ovfbin, ovfcnt);
    k_region<<<NREG, 512, 0, stream>>>(rec, cursor, ovf4, ovfbin, ovfcnt, out);
}

// Round 9
// 99.081 us; speedup vs baseline: 1.8897x; 1.0262x over previous
//
#include <hip/hip_runtime.h>

#define BOX   256
#define NCLS  2
#define BATCH 2
#define NPTS  262144                      // 2^18
#define VOL   (BOX * BOX * BOX)
#define NPTOT (BATCH * NPTS)
#define NBINS (BATCH * BOX * BOX)         // (b, base_z, base_y) row-bins = 131072
#define CAP   16                          // records per bin (Poisson mean 4)
#define CAPSH 4
#define RY    8                           // rows per region tile
#define NT    (BOX / RY)                  // 32 y-tiles per plane
#define NREG  (BATCH * BOX * NT)          // 16384 region blocks
#define NBMETA (2 * (RY + 1))             // 18: 2 planes x 9 rows per region

typedef float vfloat4 __attribute__((ext_vector_type(4)));   // clang-native for NT stores

__global__ __launch_bounds__(256) void k_zero(float4* __restrict__ p, int n4)
{
    const int i = blockIdx.x * 256 + threadIdx.x;
    if (i < n4) p[i] = make_float4(0.f, 0.f, 0.f, 0.f);
}

// ---------------------------------------------------------------------------
// Pass 1: one atomic per point -> slot in capacity-binned record array.
// Record = {px, pack16(ry,rz), v0, v1} (16 B). Overflow (~1e-6/bin) -> list.
// ---------------------------------------------------------------------------
__global__ __launch_bounds__(256) void k_place(const float* __restrict__ pts,
                                               const float* __restrict__ vals,
                                               unsigned* __restrict__ cursor,
                                               float4* __restrict__ rec,
                                               float4* __restrict__ ovf4,
                                               unsigned* __restrict__ ovfbin,
                                               unsigned* __restrict__ ovfcnt)
{
    const int tid = blockIdx.x * 256 + threadIdx.x;   // exactly NPTOT threads
    const int b = tid >> 18;
    const int n = tid & (NPTS - 1);

    const float* pp = pts + (size_t)tid * 3;
    const float px = (pp[0] + 0.5f) * (float)BOX;
    const float py = (pp[1] + 0.5f) * (float)BOX;
    const float pz = (pp[2] + 0.5f) * (float)BOX;

    const float fy = floorf(py), fz = floorf(pz);
    const int by = (int)fy, bz = (int)fz;
    const float ry = py - fy, rz = pz - fz;

    const unsigned qy = (unsigned)(ry * 65536.0f);
    const unsigned qz = (unsigned)(rz * 65536.0f);
    const unsigned packed = (qz << 16) | (qy & 0xffffu);

    const float v0 = vals[(size_t)(b * 2) * NPTS + n];
    const float v1 = vals[(size_t)(b * 2 + 1) * NPTS + n];
    const float4 r = make_float4(px, __uint_as_float(packed), v0, v1);

    const unsigned bin = ((unsigned)b << 16) | ((unsigned)bz << 8) | (unsigned)by;
    const unsigned slot = atomicAdd(&cursor[bin], 1u);
    if (slot < CAP) {
        rec[((size_t)bin << CAPSH) + slot] = r;
    } else {
        const unsigned o = atomicAdd(ovfcnt, 1u);
        ovf4[o] = r;
        ovfbin[o] = bin;
    }
}

// ---------------------------------------------------------------------------
// Pass 2: one block per (b, z-plane P, y-tile T of 8 rows). 256 threads,
// 16 KB LDS -> 8 resident blocks/CU for deep store/compute interleave.
// Meta + ovfcnt loads issued BEFORE the LDS zero (latency hides under it).
// One-shot gather: thread (j=t>>4, k=t&15) takes record k of bin j;
// bins 16,17 by wave-0 lanes. Non-temporal coalesced output stores.
// ---------------------------------------------------------------------------
__global__ __launch_bounds__(256, 8) void k_region(const float4* __restrict__ rec,
                                                   const unsigned* __restrict__ cursor,
                                                   const float4* __restrict__ ovf4,
                                                   const unsigned* __restrict__ ovfbin,
                                                   const unsigned* __restrict__ ovfcnt,
                                                   float* __restrict__ out)
{
    __shared__ float acc[NCLS * RY * BOX];      // 16 KB
    __shared__ unsigned s_base[NBMETA];
    __shared__ unsigned s_len[NBMETA];

    const int t = threadIdx.x;
    const int bid = blockIdx.x;
    const int b = bid >> 13;
    const int P = (bid >> 5) & 255;             // owned z-plane
    const int T = bid & 31;                     // owned y-tile (rows 8T..8T+7)

    // ---- issue global loads FIRST (meta + overflow count) ----
    unsigned m_len = 0, m_base = 0;
    if (t < NBMETA) {
        const int ps = (t >= RY + 1);
        const int zsrc = P - 1 + ps;
        const int y0 = RY * T - 1 + (t - (RY + 1) * ps);
        if (zsrc >= 0 && y0 >= 0) {             // y0 <= 255 structurally
            const unsigned bin = ((unsigned)b << 16) | ((unsigned)zsrc << 8) | (unsigned)y0;
            m_len = cursor[bin];                 // load issues here
            m_base = bin << CAPSH;
        }
    }
    const int oc = (int)*ovfcnt;                 // scalar load, issues early

    // ---- zero LDS tile while loads are in flight ----
    {
        float4* a4 = (float4*)acc;
        #pragma unroll
        for (int i = 0; i < 4; ++i)
            a4[i * 256 + t] = make_float4(0.f, 0.f, 0.f, 0.f);
    }
    if (t < NBMETA) {
        s_len[t] = (m_len > CAP) ? CAP : m_len;
        s_base[t] = m_base;
    }
    __syncthreads();

    // ---- one-shot record processing ----
    {
        auto process = [&](int j, int k) {
            if (k < (int)s_len[j]) {
                const float4 q = rec[(size_t)s_base[j] + k];
                const unsigned pk = __float_as_uint(q.y);
                const float ry = (float)(pk & 0xffffu) * (1.0f / 65536.0f);
                const float rz = (float)(pk >> 16) * (1.0f / 65536.0f);
                const float fx = floorf(q.x);
                const float rx = q.x - fx;
                const int ix = (int)fx;
                const int ps = (j >= RY + 1);
                const float wz = ps ? (1.0f - rz) : rz;
                const int yy0 = (j - (RY + 1) * ps) - 1;
                #pragma unroll
                for (int dy = 0; dy < 2; ++dy) {
                    const int yy = yy0 + dy;
                    if ((unsigned)yy < RY) {
                        const float wzy = wz * (dy ? ry : 1.0f - ry);
                        #pragma unroll
                        for (int dx = 0; dx < 2; ++dx) {
                            const int x = ix + dx;
                            if (x < BOX) {
                                const float w = wzy * (dx ? rx : 1.0f - rx);
                                const int li = yy * BOX + x;
                                atomicAdd(&acc[li], w * q.z);
                                atomicAdd(&acc[RY * BOX + li], w * q.w);
                            }
                        }
                    }
                }
            }
        };
        process(t >> 4, t & 15);                     // bins 0..15
        if (t < 32) process(16 + (t >> 4), t & 15);  // bins 16,17
    }

    // ---- overflow records (essentially never; correctness path) ----
    for (int r = t; r < oc; r += 256) {
        const unsigned bin = ovfbin[r];
        if ((int)(bin >> 16) != b) continue;
        const int bz = (int)((bin >> 8) & 255u);
        if (bz != P && bz != P - 1) continue;
        const int by = (int)(bin & 255u);
        const int yy0 = by - RY * T;
        if (yy0 < -1 || yy0 > RY - 1) continue;

        const float4 q = ovf4[r];
        const unsigned pk = __float_as_uint(q.y);
        const float ry = (float)(pk & 0xffffu) * (1.0f / 65536.0f);
        const float rz = (float)(pk >> 16) * (1.0f / 65536.0f);
        const float fx = floorf(q.x);
        const float rx = q.x - fx;
        const int ix = (int)fx;
        const float wz = (bz == P) ? (1.0f - rz) : rz;

        for (int dy = 0; dy < 2; ++dy) {
            const int yy = yy0 + dy;
            if ((unsigned)yy < RY) {
                const float wzy = wz * (dy ? ry : 1.0f - ry);
                for (int dx = 0; dx < 2; ++dx) {
                    const int x = ix + dx;
                    if (x < BOX) {
                        const float w = wzy * (dx ? rx : 1.0f - rx);
                        const int li = yy * BOX + x;
                        atomicAdd(&acc[li], w * q.z);
                        atomicAdd(&acc[RY * BOX + li], w * q.w);
                    }
                }
            }
        }
    }
    __syncthreads();

    // ---- non-temporal coalesced store (output never re-read) ----
    #pragma unroll
    for (int c = 0; c < NCLS; ++c) {
        const size_t o4base = (size_t)((b * NCLS + c) * BOX + P) * (BOX * BOX / 4)
                              + (size_t)T * (RY * BOX / 4);
        vfloat4* o4 = (vfloat4*)out;
        const vfloat4* a4 = (const vfloat4*)(acc + c * RY * BOX);
        #pragma unroll
        for (int i = 0; i < 2; ++i)
            __builtin_nontemporal_store(a4[i * 256 + t], &o4[o4base + i * 256 + t]);
    }
}

// ---------------------------------------------------------------------------
// Fallback: plain global-atomic scatter (only if ws too small).
// ---------------------------------------------------------------------------
__global__ __launch_bounds__(256) void cic_scatter_kernel(
    const float* __restrict__ points, const float* __restrict__ values,
    float* __restrict__ out)
{
    const int tid = blockIdx.x * blockDim.x + threadIdx.x;
    if (tid >= NPTOT) return;
    const int b = tid >> 18, n = tid & (NPTS - 1);
    const float* pp = points + (size_t)tid * 3;
    const float px = (pp[0] + 0.5f) * BOX, py = (pp[1] + 0.5f) * BOX, pz = (pp[2] + 0.5f) * BOX;
    const float fx = floorf(px), fy = floorf(py), fz = floorf(pz);
    const float rx = px - fx, ry = py - fy, rz = pz - fz;
    const int ix = (int)fx, iy = (int)fy, iz = (int)fz;
    const float v0 = values[(size_t)(b * 2) * NPTS + n];
    const float v1 = values[(size_t)(b * 2 + 1) * NPTS + n];
    const float wx[2] = {1.f - rx, rx}, wy[2] = {1.f - ry, ry}, wz[2] = {1.f - rz, rz};
    float* out0 = out + (size_t)(b * 2) * VOL;
    float* out1 = out + (size_t)(b * 2 + 1) * VOL;
    for (int dz = 0; dz < 2; ++dz) {
        const int z = iz + dz; if (z >= BOX) continue;
        for (int dy = 0; dy < 2; ++dy) {
            const int y = iy + dy; if (y >= BOX) continue;
            const float wzy = wz[dz] * wy[dy];
            const int rowbase = (z * BOX + y) * BOX;
            for (int dx = 0; dx < 2; ++dx) {
                const int x = ix + dx; if (x >= BOX) continue;
                atomicAdd(out0 + rowbase + x, wzy * wx[dx] * v0);
                atomicAdd(out1 + rowbase + x, wzy * wx[dx] * v1);
            }
        }
    }
}

extern "C" void kernel_launch(void* const* d_in, const int* in_sizes, int n_in,
                              void* d_out, int out_size, void* d_ws, size_t ws_size,
                              hipStream_t stream) {
    const float* points = (const float*)d_in[0];   // [B, N, 3]
    const float* values = (const float*)d_in[1];   // [B, C, N]
    float* out = (float*)d_out;                    // [B, C, 256,256,256]

    const size_t CUR_OFF  = 0;                                   // NBINS u32
    const size_t OVFC_OFF = (size_t)NBINS * 4;                   // 1 u32 (+pad)
    const size_t REC_OFF  = OVFC_OFF + 256;                      // NBINS*CAP*16 B
    const size_t OVF4_OFF = REC_OFF + (size_t)NBINS * CAP * 16;
    const size_t OVFB_OFF = OVF4_OFF + (size_t)NPTOT * 16;
    const size_t WS_NEED  = OVFB_OFF + (size_t)NPTOT * 4;

    if (ws_size < WS_NEED) {
        (void)hipMemsetAsync(out, 0, (size_t)out_size * sizeof(float), stream);
        cic_scatter_kernel<<<NPTOT / 256, 256, 0, stream>>>(points, values, out);
        return;
    }

    char* ws = (char*)d_ws;
    unsigned* cursor = (unsigned*)(ws + CUR_OFF);
    unsigned* ovfcnt = (unsigned*)(ws + OVFC_OFF);
    float4*   rec    = (float4*)(ws + REC_OFF);
    float4*   ovf4   = (float4*)(ws + OVF4_OFF);
    unsigned* ovfbin = (unsigned*)(ws + OVFB_OFF);

    const int n4 = (int)((OVFC_OFF + 256) / 16);   // 32784 float4s
    k_zero<<<(n4 + 255) / 256, 256, 0, stream>>>((float4*)ws, n4);

    k_place<<<NPTOT / 256, 256, 0, stream>>>(points, values, cursor,
                                             rec, ovf4, ovfbin, ovfcnt);
    k_region<<<NREG, 256, 0, stream>>>(rec, cursor, ovf4, ovfbin, ovfcnt, out);
}

// Round 10
// 98.894 us; speedup vs baseline: 1.8933x; 1.0019x over previous
//
#include <hip/hip_runtime.h>

#define BOX   256
#define NCLS  2
#define BATCH 2
#define NPTS  262144                      // 2^18
#define VOL   (BOX * BOX * BOX)
#define NPTOT (BATCH * NPTS)
#define NBINS (BATCH * BOX * BOX)         // (b, base_z, base_y) row-bins = 131072
#define CAP   16                          // records per bin (Poisson mean 4)
#define CAPSH 4
#define RY    8                           // rows per region tile
#define NT    (BOX / RY)                  // 32 y-tiles per plane
#define NREG  (BATCH * BOX * NT)          // 16384 region blocks

typedef float vfloat4 __attribute__((ext_vector_type(4)));   // clang-native for NT stores

__global__ __launch_bounds__(256) void k_zero(float4* __restrict__ p, int n4)
{
    const int i = blockIdx.x * 256 + threadIdx.x;
    if (i < n4) p[i] = make_float4(0.f, 0.f, 0.f, 0.f);
}

// ---------------------------------------------------------------------------
// Pass 1: one atomic per point -> slot in capacity-binned record array.
// Record = {px, pack16(ry,rz), v0, v1} (16 B). Overflow (~1e-6/bin) -> list.
// ---------------------------------------------------------------------------
__global__ __launch_bounds__(256) void k_place(const float* __restrict__ pts,
                                               const float* __restrict__ vals,
                                               unsigned* __restrict__ cursor,
                                               float4* __restrict__ rec,
                                               float4* __restrict__ ovf4,
                                               unsigned* __restrict__ ovfbin,
                                               unsigned* __restrict__ ovfcnt)
{
    const int tid = blockIdx.x * 256 + threadIdx.x;   // exactly NPTOT threads
    const int b = tid >> 18;
    const int n = tid & (NPTS - 1);

    const float* pp = pts + (size_t)tid * 3;
    const float px = (pp[0] + 0.5f) * (float)BOX;
    const float py = (pp[1] + 0.5f) * (float)BOX;
    const float pz = (pp[2] + 0.5f) * (float)BOX;

    const float fy = floorf(py), fz = floorf(pz);
    const int by = (int)fy, bz = (int)fz;
    const float ry = py - fy, rz = pz - fz;

    const unsigned qy = (unsigned)(ry * 65536.0f);
    const unsigned qz = (unsigned)(rz * 65536.0f);
    const unsigned packed = (qz << 16) | (qy & 0xffffu);

    const float v0 = vals[(size_t)(b * 2) * NPTS + n];
    const float v1 = vals[(size_t)(b * 2 + 1) * NPTS + n];
    const float4 r = make_float4(px, __uint_as_float(packed), v0, v1);

    const unsigned bin = ((unsigned)b << 16) | ((unsigned)bz << 8) | (unsigned)by;
    const unsigned slot = atomicAdd(&cursor[bin], 1u);
    if (slot < CAP) {
        rec[((size_t)bin << CAPSH) + slot] = r;
    } else {
        const unsigned o = atomicAdd(ovfcnt, 1u);
        ovf4[o] = r;
        ovfbin[o] = bin;
    }
}

// ---------------------------------------------------------------------------
// Pass 2: one block per (b, z-plane P, y-tile T of 8 rows). 256 threads.
// Front chain collapsed: per-lane broadcast cursor loads (no meta LDS, no
// first barrier) + register prefetch of records issued BEFORE the LDS zero.
// Bins: j in [0,18). j<9 -> plane P-1 rows 8T-1..8T+7 ; j>=9 -> plane P same
// rows. Thread t covers (j=t>>4, k=t&15); lanes 0..31 additionally cover
// bins 16,17. 2 barriers total. Non-temporal coalesced output stores.
// ---------------------------------------------------------------------------
__global__ __launch_bounds__(256, 8) void k_region(const float4* __restrict__ rec,
                                                   const unsigned* __restrict__ cursor,
                                                   const float4* __restrict__ ovf4,
                                                   const unsigned* __restrict__ ovfbin,
                                                   const unsigned* __restrict__ ovfcnt,
                                                   float* __restrict__ out)
{
    __shared__ float acc[NCLS * RY * BOX];      // 16 KB

    const int t = threadIdx.x;
    const int bid = blockIdx.x;
    const int b = bid >> 13;
    const int P = (bid >> 5) & 255;             // owned z-plane
    const int T = bid & 31;                     // owned y-tile (rows 8T..8T+7)

    // ---- per-lane meta + record prefetch (issued before anything else) ----
    const int j1 = t >> 4, k1 = t & 15;
    unsigned len1 = 0; size_t base1 = 0;
    {
        const int ps = (j1 >= 9);
        const int zsrc = P - 1 + ps;
        const int y0 = RY * T - 1 + (j1 - 9 * ps);
        if (zsrc >= 0 && y0 >= 0) {
            const unsigned bin = ((unsigned)b << 16) | ((unsigned)zsrc << 8) | (unsigned)y0;
            len1 = cursor[bin];                 // 16-lane hardware broadcast
            if (len1 > CAP) len1 = CAP;
            base1 = (size_t)bin << CAPSH;
        }
    }
    const bool h1 = (k1 < (int)len1);
    float4 q1 = make_float4(0.f, 0.f, 0.f, 0.f);
    if (h1) q1 = rec[base1 + k1];               // prefetch; latency hides under zero

    bool h2 = false;
    float4 q2 = make_float4(0.f, 0.f, 0.f, 0.f);
    int j2 = 16;
    if (t < 32) {
        j2 = 16 + (t >> 4);                     // 16 or 17 -> plane P, rows 8T+6, 8T+7
        const int y0 = RY * T - 1 + (j2 - 9);
        const unsigned bin = ((unsigned)b << 16) | ((unsigned)P << 8) | (unsigned)y0;
        unsigned len2 = cursor[bin];
        if (len2 > CAP) len2 = CAP;
        h2 = ((t & 15) < (int)len2);
        if (h2) q2 = rec[((size_t)bin << CAPSH) + (t & 15)];
    }
    const int oc = (int)*ovfcnt;                // uniform scalar load

    // ---- zero LDS tile while loads are in flight ----
    {
        float4* a4 = (float4*)acc;
        #pragma unroll
        for (int i = 0; i < 4; ++i)
            a4[i * 256 + t] = make_float4(0.f, 0.f, 0.f, 0.f);
    }
    __syncthreads();

    // ---- record processing (records already in registers) ----
    {
        auto process = [&](const float4& q, int j, bool valid) {
            if (valid) {
                const unsigned pk = __float_as_uint(q.y);
                const float ry = (float)(pk & 0xffffu) * (1.0f / 65536.0f);
                const float rz = (float)(pk >> 16) * (1.0f / 65536.0f);
                const float fx = floorf(q.x);
                const float rx = q.x - fx;
                const int ix = (int)fx;
                const int ps = (j >= 9);
                const float wz = ps ? (1.0f - rz) : rz;
                const int yy0 = (j - 9 * ps) - 1;
                #pragma unroll
                for (int dy = 0; dy < 2; ++dy) {
                    const int yy = yy0 + dy;
                    if ((unsigned)yy < RY) {
                        const float wzy = wz * (dy ? ry : 1.0f - ry);
                        #pragma unroll
                        for (int dx = 0; dx < 2; ++dx) {
                            const int x = ix + dx;
                            if (x < BOX) {
                                const float w = wzy * (dx ? rx : 1.0f - rx);
                                const int li = yy * BOX + x;
                                atomicAdd(&acc[li], w * q.z);
                                atomicAdd(&acc[RY * BOX + li], w * q.w);
                            }
                        }
                    }
                }
            }
        };
        process(q1, j1, h1);
        process(q2, j2, h2);
    }

    // ---- overflow records (essentially never; correctness path) ----
    for (int r = t; r < oc; r += 256) {
        const unsigned bin = ovfbin[r];
        if ((int)(bin >> 16) != b) continue;
        const int bz = (int)((bin >> 8) & 255u);
        if (bz != P && bz != P - 1) continue;
        const int by = (int)(bin & 255u);
        const int yy0 = by - RY * T;
        if (yy0 < -1 || yy0 > RY - 1) continue;

        const float4 q = ovf4[r];
        const unsigned pk = __float_as_uint(q.y);
        const float ry = (float)(pk & 0xffffu) * (1.0f / 65536.0f);
        const float rz = (float)(pk >> 16) * (1.0f / 65536.0f);
        const float fx = floorf(q.x);
        const float rx = q.x - fx;
        const int ix = (int)fx;
        const float wz = (bz == P) ? (1.0f - rz) : rz;

        for (int dy = 0; dy < 2; ++dy) {
            const int yy = yy0 + dy;
            if ((unsigned)yy < RY) {
                const float wzy = wz * (dy ? ry : 1.0f - ry);
                for (int dx = 0; dx < 2; ++dx) {
                    const int x = ix + dx;
                    if (x < BOX) {
                        const float w = wzy * (dx ? rx : 1.0f - rx);
                        const int li = yy * BOX + x;
                        atomicAdd(&acc[li], w * q.z);
                        atomicAdd(&acc[RY * BOX + li], w * q.w);
                    }
                }
            }
        }
    }
    __syncthreads();

    // ---- non-temporal coalesced store (output never re-read) ----
    #pragma unroll
    for (int c = 0; c < NCLS; ++c) {
        const size_t o4base = (size_t)((b * NCLS + c) * BOX + P) * (BOX * BOX / 4)
                              + (size_t)T * (RY * BOX / 4);
        vfloat4* o4 = (vfloat4*)out;
        const vfloat4* a4 = (const vfloat4*)(acc + c * RY * BOX);
        #pragma unroll
        for (int i = 0; i < 2; ++i)
            __builtin_nontemporal_store(a4[i * 256 + t], &o4[o4base + i * 256 + t]);
    }
}

// ---------------------------------------------------------------------------
// Fallback: plain global-atomic scatter (only if ws too small).
// ---------------------------------------------------------------------------
__global__ __launch_bounds__(256) void cic_scatter_kernel(
    const float* __restrict__ points, const float* __restrict__ values,
    float* __restrict__ out)
{
    const int tid = blockIdx.x * blockDim.x + threadIdx.x;
    if (tid >= NPTOT) return;
    const int b = tid >> 18, n = tid & (NPTS - 1);
    const float* pp = points + (size_t)tid * 3;
    const float px = (pp[0] + 0.5f) * BOX, py = (pp[1] + 0.5f) * BOX, pz = (pp[2] + 0.5f) * BOX;
    const float fx = floorf(px), fy = floorf(py), fz = floorf(pz);
    const float rx = px - fx, ry = py - fy, rz = pz - fz;
    const int ix = (int)fx, iy = (int)fy, iz = (int)fz;
    const float v0 = values[(size_t)(b * 2) * NPTS + n];
    const float v1 = values[(size_t)(b * 2 + 1) * NPTS + n];
    const float wx[2] = {1.f - rx, rx}, wy[2] = {1.f - ry, ry}, wz[2] = {1.f - rz, rz};
    float* out0 = out + (size_t)(b * 2) * VOL;
    float* out1 = out + (size_t)(b * 2 + 1) * VOL;
    for (int dz = 0; dz < 2; ++dz) {
        const int z = iz + dz; if (z >= BOX) continue;
        for (int dy = 0; dy < 2; ++dy) {
            const int y = iy + dy; if (y >= BOX) continue;
            const float wzy = wz[dz] * wy[dy];
            const int rowbase = (z * BOX + y) * BOX;
            for (int dx = 0; dx < 2; ++dx) {
                const int x = ix + dx; if (x >= BOX) continue;
                atomicAdd(out0 + rowbase + x, wzy * wx[dx] * v0);
                atomicAdd(out1 + rowbase + x, wzy * wx[dx] * v1);
            }
        }
    }
}

extern "C" void kernel_launch(void* const* d_in, const int* in_sizes, int n_in,
                              void* d_out, int out_size, void* d_ws, size_t ws_size,
                              hipStream_t stream) {
    const float* points = (const float*)d_in[0];   // [B, N, 3]
    const float* values = (const float*)d_in[1];   // [B, C, N]
    float* out = (float*)d_out;                    // [B, C, 256,256,256]

    const size_t CUR_OFF  = 0;                                   // NBINS u32
    const size_t OVFC_OFF = (size_t)NBINS * 4;                   // 1 u32 (+pad)
    const size_t REC_OFF  = OVFC_OFF + 256;                      // NBINS*CAP*16 B
    const size_t OVF4_OFF = REC_OFF + (size_t)NBINS * CAP * 16;
    const size_t OVFB_OFF = OVF4_OFF + (size_t)NPTOT * 16;
    const size_t WS_NEED  = OVFB_OFF + (size_t)NPTOT * 4;

    if (ws_size < WS_NEED) {
        (void)hipMemsetAsync(out, 0, (size_t)out_size * sizeof(float), stream);
        cic_scatter_kernel<<<NPTOT / 256, 256, 0, stream>>>(points, values, out);
        return;
    }

    char* ws = (char*)d_ws;
    unsigned* cursor = (unsigned*)(ws + CUR_OFF);
    unsigned* ovfcnt = (unsigned*)(ws + OVFC_OFF);
    float4*   rec    = (float4*)(ws + REC_OFF);
    float4*   ovf4   = (float4*)(ws + OVF4_OFF);
    unsigned* ovfbin = (unsigned*)(ws + OVFB_OFF);

    const int n4 = (int)((OVFC_OFF + 256) / 16);   // 32784 float4s
    k_zero<<<(n4 + 255) / 256, 256, 0, stream>>>((float4*)ws, n4);

    k_place<<<NPTOT / 256, 256, 0, stream>>>(points, values, cursor,
                                             rec, ovf4, ovfbin, ovfcnt);
    k_region<<<NREG, 256, 0, stream>>>(rec, cursor, ovf4, ovfbin, ovfcnt, out);
}

// Round 11
// 90.817 us; speedup vs baseline: 2.0617x; 1.0889x over previous
//
#include <hip/hip_runtime.h>

#define BOX   256
#define NCLS  2
#define BATCH 2
#define NPTS  262144                      // 2^18
#define VOL   (BOX * BOX * BOX)
#define NPTOT (BATCH * NPTS)
#define NBINS (BATCH * BOX * BOX)         // (b, base_z, base_y) row-bins = 131072
#define CAP   16                          // records per bin (Poisson mean 4)
#define CAPSH 4
#define RY    8                           // rows per region tile
#define NT    (BOX / RY)                  // 32 y-tiles per plane
#define NREG  (BATCH * BOX * NT)          // 16384 region blocks

typedef float vfloat4 __attribute__((ext_vector_type(4)));   // clang-native for NT stores

__device__ __forceinline__ unsigned bf16_rne(float v) {
    unsigned u = __float_as_uint(v);
    u += 0x7fffu + ((u >> 16) & 1u);      // round-to-nearest-even
    return u >> 16;
}
__device__ __forceinline__ float bf16_to_f(unsigned h) {
    return __uint_as_float(h << 16);
}

__global__ __launch_bounds__(256) void k_zero(float4* __restrict__ p, int n4)
{
    const int i = blockIdx.x * 256 + threadIdx.x;
    if (i < n4) p[i] = make_float4(0.f, 0.f, 0.f, 0.f);
}

// ---------------------------------------------------------------------------
// Pass 1: one atomic per point -> slot in capacity-binned record array.
// Record = 8 B: {ix:8|qx:8|qy:8|qz:8 , v0:bf16|v1:bf16}. Overflow -> list.
// 8B records halve the scattered-store dirty footprint (rec = 16.8 MB).
// ---------------------------------------------------------------------------
__global__ __launch_bounds__(256) void k_place(const float* __restrict__ pts,
                                               const float* __restrict__ vals,
                                               unsigned* __restrict__ cursor,
                                               uint2* __restrict__ rec,
                                               uint2* __restrict__ ovf2,
                                               unsigned* __restrict__ ovfbin,
                                               unsigned* __restrict__ ovfcnt)
{
    const int tid = blockIdx.x * 256 + threadIdx.x;   // exactly NPTOT threads
    const int b = tid >> 18;
    const int n = tid & (NPTS - 1);

    const float* pp = pts + (size_t)tid * 3;
    const float px = (pp[0] + 0.5f) * (float)BOX;
    const float py = (pp[1] + 0.5f) * (float)BOX;
    const float pz = (pp[2] + 0.5f) * (float)BOX;

    const float fx = floorf(px), fy = floorf(py), fz = floorf(pz);
    const int ix = (int)fx, by = (int)fy, bz = (int)fz;

    // 8-bit fracs scaled by 255 (max err 0.5/255 per axis)
    const unsigned qx = (unsigned)((px - fx) * 255.0f + 0.5f);
    const unsigned qy = (unsigned)((py - fy) * 255.0f + 0.5f);
    const unsigned qz = (unsigned)((pz - fz) * 255.0f + 0.5f);

    const float v0 = vals[(size_t)(b * 2) * NPTS + n];
    const float v1 = vals[(size_t)(b * 2 + 1) * NPTS + n];

    uint2 r;
    r.x = (unsigned)ix | (qx << 8) | (qy << 16) | (qz << 24);
    r.y = bf16_rne(v0) | (bf16_rne(v1) << 16);

    const unsigned bin = ((unsigned)b << 16) | ((unsigned)bz << 8) | (unsigned)by;
    const unsigned slot = atomicAdd(&cursor[bin], 1u);
    if (slot < CAP) {
        rec[((size_t)bin << CAPSH) + slot] = r;
    } else {
        const unsigned o = atomicAdd(ovfcnt, 1u);
        ovf2[o] = r;
        ovfbin[o] = bin;
    }
}

// ---------------------------------------------------------------------------
// Pass 2: one block per (b, z-plane P, y-tile T of 8 rows). 256 threads,
// 16 KB LDS, 8 blocks/CU. Per-lane broadcast cursor loads + register record
// prefetch before the LDS zero. Bin j<9 -> plane P-1 rows 8T-1..8T+7;
// j>=9 -> plane P. Thread t: (j=t>>4, k=t&15); lanes 0..31 cover bins 16,17.
// 2 barriers. Non-temporal coalesced output stores.
// ---------------------------------------------------------------------------
__global__ __launch_bounds__(256, 8) void k_region(const uint2* __restrict__ rec,
                                                   const unsigned* __restrict__ cursor,
                                                   const uint2* __restrict__ ovf2,
                                                   const unsigned* __restrict__ ovfbin,
                                                   const unsigned* __restrict__ ovfcnt,
                                                   float* __restrict__ out)
{
    __shared__ float acc[NCLS * RY * BOX];      // 16 KB

    const int t = threadIdx.x;
    const int bid = blockIdx.x;
    const int b = bid >> 13;
    const int P = (bid >> 5) & 255;             // owned z-plane
    const int T = bid & 31;                     // owned y-tile (rows 8T..8T+7)

    // ---- per-lane meta + record prefetch (issued before anything else) ----
    const int j1 = t >> 4, k1 = t & 15;
    unsigned len1 = 0; size_t base1 = 0;
    {
        const int ps = (j1 >= 9);
        const int zsrc = P - 1 + ps;
        const int y0 = RY * T - 1 + (j1 - 9 * ps);
        if (zsrc >= 0 && y0 >= 0) {
            const unsigned bin = ((unsigned)b << 16) | ((unsigned)zsrc << 8) | (unsigned)y0;
            len1 = cursor[bin];                 // 16-lane hardware broadcast
            if (len1 > CAP) len1 = CAP;
            base1 = (size_t)bin << CAPSH;
        }
    }
    const bool h1 = (k1 < (int)len1);
    uint2 q1 = make_uint2(0u, 0u);
    if (h1) q1 = rec[base1 + k1];               // prefetch; hides under zero

    bool h2 = false;
    uint2 q2 = make_uint2(0u, 0u);
    int j2 = 16;
    if (t < 32) {
        j2 = 16 + (t >> 4);                     // bins 16,17 -> plane P rows 8T+6..7
        const int y0 = RY * T - 1 + (j2 - 9);
        const unsigned bin = ((unsigned)b << 16) | ((unsigned)P << 8) | (unsigned)y0;
        unsigned len2 = cursor[bin];
        if (len2 > CAP) len2 = CAP;
        h2 = ((t & 15) < (int)len2);
        if (h2) q2 = rec[((size_t)bin << CAPSH) + (t & 15)];
    }
    const int oc = (int)*ovfcnt;                // uniform scalar load

    // ---- zero LDS tile while loads are in flight ----
    {
        float4* a4 = (float4*)acc;
        #pragma unroll
        for (int i = 0; i < 4; ++i)
            a4[i * 256 + t] = make_float4(0.f, 0.f, 0.f, 0.f);
    }
    __syncthreads();

    // ---- record processing (records already in registers) ----
    {
        auto process = [&](const uint2& q, int j, bool valid) {
            if (valid) {
                const int ix = (int)(q.x & 255u);
                const float rx = (float)((q.x >> 8) & 255u) * (1.0f / 255.0f);
                const float ry = (float)((q.x >> 16) & 255u) * (1.0f / 255.0f);
                const float rz = (float)(q.x >> 24) * (1.0f / 255.0f);
                const float v0 = bf16_to_f(q.y & 0xffffu);
                const float v1 = bf16_to_f(q.y >> 16);
                const int ps = (j >= 9);
                const float wz = ps ? (1.0f - rz) : rz;
                const int yy0 = (j - 9 * ps) - 1;
                #pragma unroll
                for (int dy = 0; dy < 2; ++dy) {
                    const int yy = yy0 + dy;
                    if ((unsigned)yy < RY) {
                        const float wzy = wz * (dy ? ry : 1.0f - ry);
                        #pragma unroll
                        for (int dx = 0; dx < 2; ++dx) {
                            const int x = ix + dx;
                            if (x < BOX) {
                                const float w = wzy * (dx ? rx : 1.0f - rx);
                                const int li = yy * BOX + x;
                                atomicAdd(&acc[li], w * v0);
                                atomicAdd(&acc[RY * BOX + li], w * v1);
                            }
                        }
                    }
                }
            }
        };
        process(q1, j1, h1);
        process(q2, j2, h2);
    }

    // ---- overflow records (essentially never; correctness path) ----
    for (int r = t; r < oc; r += 256) {
        const unsigned bin = ovfbin[r];
        if ((int)(bin >> 16) != b) continue;
        const int bz = (int)((bin >> 8) & 255u);
        if (bz != P && bz != P - 1) continue;
        const int by = (int)(bin & 255u);
        const int yy0 = by - RY * T;
        if (yy0 < -1 || yy0 > RY - 1) continue;

        const uint2 q = ovf2[r];
        const int ix = (int)(q.x & 255u);
        const float rx = (float)((q.x >> 8) & 255u) * (1.0f / 255.0f);
        const float ry = (float)((q.x >> 16) & 255u) * (1.0f / 255.0f);
        const float rz = (float)(q.x >> 24) * (1.0f / 255.0f);
        const float v0 = bf16_to_f(q.y & 0xffffu);
        const float v1 = bf16_to_f(q.y >> 16);
        const float wz = (bz == P) ? (1.0f - rz) : rz;

        for (int dy = 0; dy < 2; ++dy) {
            const int yy = yy0 + dy;
            if ((unsigned)yy < RY) {
                const float wzy = wz * (dy ? ry : 1.0f - ry);
                for (int dx = 0; dx < 2; ++dx) {
                    const int x = ix + dx;
                    if (x < BOX) {
                        const float w = wzy * (dx ? rx : 1.0f - rx);
                        const int li = yy * BOX + x;
                        atomicAdd(&acc[li], w * v0);
                        atomicAdd(&acc[RY * BOX + li], w * v1);
                    }
                }
            }
        }
    }
    __syncthreads();

    // ---- non-temporal coalesced store (output never re-read) ----
    #pragma unroll
    for (int c = 0; c < NCLS; ++c) {
        const size_t o4base = (size_t)((b * NCLS + c) * BOX + P) * (BOX * BOX / 4)
                              + (size_t)T * (RY * BOX / 4);
        vfloat4* o4 = (vfloat4*)out;
        const vfloat4* a4 = (const vfloat4*)(acc + c * RY * BOX);
        #pragma unroll
        for (int i = 0; i < 2; ++i)
            __builtin_nontemporal_store(a4[i * 256 + t], &o4[o4base + i * 256 + t]);
    }
}

// ---------------------------------------------------------------------------
// Fallback: plain global-atomic scatter (only if ws too small).
// ---------------------------------------------------------------------------
__global__ __launch_bounds__(256) void cic_scatter_kernel(
    const float* __restrict__ points, const float* __restrict__ values,
    float* __restrict__ out)
{
    const int tid = blockIdx.x * blockDim.x + threadIdx.x;
    if (tid >= NPTOT) return;
    const int b = tid >> 18, n = tid & (NPTS - 1);
    const float* pp = points + (size_t)tid * 3;
    const float px = (pp[0] + 0.5f) * BOX, py = (pp[1] + 0.5f) * BOX, pz = (pp[2] + 0.5f) * BOX;
    const float fx = floorf(px), fy = floorf(py), fz = floorf(pz);
    const float rx = px - fx, ry = py - fy, rz = pz - fz;
    const int ix = (int)fx, iy = (int)fy, iz = (int)fz;
    const float v0 = values[(size_t)(b * 2) * NPTS + n];
    const float v1 = values[(size_t)(b * 2 + 1) * NPTS + n];
    const float wx[2] = {1.f - rx, rx}, wy[2] = {1.f - ry, ry}, wz[2] = {1.f - rz, rz};
    float* out0 = out + (size_t)(b * 2) * VOL;
    float* out1 = out + (size_t)(b * 2 + 1) * VOL;
    for (int dz = 0; dz < 2; ++dz) {
        const int z = iz + dz; if (z >= BOX) continue;
        for (int dy = 0; dy < 2; ++dy) {
            const int y = iy + dy; if (y >= BOX) continue;
            const float wzy = wz[dz] * wy[dy];
            const int rowbase = (z * BOX + y) * BOX;
            for (int dx = 0; dx < 2; ++dx) {
                const int x = ix + dx; if (x >= BOX) continue;
                atomicAdd(out0 + rowbase + x, wzy * wx[dx] * v0);
                atomicAdd(out1 + rowbase + x, wzy * wx[dx] * v1);
            }
        }
    }
}

extern "C" void kernel_launch(void* const* d_in, const int* in_sizes, int n_in,
                              void* d_out, int out_size, void* d_ws, size_t ws_size,
                              hipStream_t stream) {
    const float* points = (const float*)d_in[0];   // [B, N, 3]
    const float* values = (const float*)d_in[1];   // [B, C, N]
    float* out = (float*)d_out;                    // [B, C, 256,256,256]

    const size_t CUR_OFF  = 0;                                   // NBINS u32
    const size_t OVFC_OFF = (size_t)NBINS * 4;                   // 1 u32 (+pad)
    const size_t REC_OFF  = OVFC_OFF + 256;                      // NBINS*CAP*8 B
    const size_t OVF2_OFF = REC_OFF + (size_t)NBINS * CAP * 8;
    const size_t OVFB_OFF = OVF2_OFF + (size_t)NPTOT * 8;
    const size_t WS_NEED  = OVFB_OFF + (size_t)NPTOT * 4;

    if (ws_size < WS_NEED) {
        (void)hipMemsetAsync(out, 0, (size_t)out_size * sizeof(float), stream);
        cic_scatter_kernel<<<NPTOT / 256, 256, 0, stream>>>(points, values, out);
        return;
    }

    char* ws = (char*)d_ws;
    unsigned* cursor = (unsigned*)(ws + CUR_OFF);
    unsigned* ovfcnt = (unsigned*)(ws + OVFC_OFF);
    uint2*    rec    = (uint2*)(ws + REC_OFF);
    uint2*    ovf2   = (uint2*)(ws + OVF2_OFF);
    unsigned* ovfbin = (unsigned*)(ws + OVFB_OFF);

    const int n4 = (int)((OVFC_OFF + 256) / 16);   // 32784 float4s
    k_zero<<<(n4 + 255) / 256, 256, 0, stream>>>((float4*)ws, n4);

    k_place<<<NPTOT / 256, 256, 0, stream>>>(points, values, cursor,
                                             rec, ovf2, ovfbin, ovfcnt);
    k_region<<<NREG, 256, 0, stream>>>(rec, cursor, ovf2, ovfbin, ovfcnt, out);
}